// Round 16
// baseline (68.132 us; speedup 1.0000x reference)
//
#include <hip/hip_runtime.h>
#include <math.h>

#define B_    32
#define C_    64
#define T_    512
#define NROWS (B_ * C_)
#define CMAX_ 16
#define FEPS  1.1920929e-07f

// gelu via sigmoid form of the tanh approximation (max abs err ~3e-4)
__device__ __forceinline__ float gelu_fast(float x) {
    float y = fmaf(0.044715f * x * x, x, x);
    float e = __builtin_exp2f(-2.3022808f * y);
    return x * __builtin_amdgcn_rcpf(1.0f + e);
}

// ---------------- mono kernel: rFFT + top-3 + fold/conv/pools/seq ----------
// One row per block, 128 threads (2 waves). Conv/pools split across waves by
// cc-halves (wave 0: cc 0..7, wave 1: cc 8..15); partials merged via LDS.
__global__ __launch_bounds__(128) void mono_kernel(
    const float* __restrict__ feat,
    const float* __restrict__ w0, const float* __restrict__ b0,
    const float* __restrict__ w1, const float* __restrict__ b1,
    const float* __restrict__ w2, const float* __restrict__ b2,
    const float* __restrict__ wpj, const float* __restrict__ bpj,
    const float* __restrict__ wr, const float* __restrict__ br,
    float* __restrict__ avg_out, float* __restrict__ max_out,
    float* __restrict__ seq_out)
{
    __shared__ float rowp[1040];         // rowp[2+i] = row[i]; tail zero-filled
    __shared__ __align__(16) float2 FA[256];   // FFT ping; later: merge buffer
    __shared__ __align__(16) float2 FB[256];   // FFT pong
    __shared__ float WeffS[80];
    __shared__ float WsumS[25];          // W0+W1+W2 (identical-fold case)
    __shared__ float wtopS[6];
    __shared__ int   itopS[6];
    __shared__ int   ipS[9];             // P[3], cyc[3], base[3]
    __shared__ float bwS[3];

    const int tid = threadIdx.x;         // 0..127
    const int lane = tid & 63;
    const int wv = tid >> 6;
    const int r = blockIdx.x;

    // ---- stage row into padded LDS; zero tail so no clamps needed ----
    {
        float4 v = reinterpret_cast<const float4*>(feat + (size_t)r * T_)[tid];
        int bi = 2 + tid * 4;
        rowp[bi + 0] = v.x; rowp[bi + 1] = v.y;
        rowp[bi + 2] = v.z; rowp[bi + 3] = v.w;
    }
    for (int i = 514 + tid; i < 1040; i += 128) rowp[i] = 0.f;
    if (tid == 0) { rowp[0] = 0.f; rowp[1] = 0.f; }
    if (tid < 80) {
        int i = tid;
        if (i < 75) {
            int k = i / 25, ij = i % 25, ii = ij / 5, jj = ij % 5;
            float w = wpj[2] * w2[k * 25 + ii * 5 + jj];
            if (ii >= 1 && ii <= 3 && jj >= 1 && jj <= 3)
                w += wpj[1] * w1[k * 9 + (ii - 1) * 3 + (jj - 1)];
            if (ii == 2 && jj == 2) w += wpj[0] * w0[k];
            WeffS[i] = w;
        } else if (i == 75) {
            WeffS[75] = wpj[0] * b0[0] + wpj[1] * b1[0] + wpj[2] * b2[0] + bpj[0];
        } else if (i <= 78) {
            WeffS[i] = wr[i - 76];
        } else {
            WeffS[79] = br[0];
        }
    }
    __syncthreads();

    // ---- pack: wave wv owns z_wv[n] = x[4n+2wv] + i x[4n+1+2wv], n=0..127 ----
    {
        float2* Fw = FA + (wv << 7);
        #pragma unroll
        for (int n = lane; n < 128; n += 64)
            Fw[n] = make_float2(rowp[2 + 4 * n + 2 * wv], rowp[3 + 4 * n + 2 * wv]);
    }

    // ---- 7-stage wave-local Stockham 128-pt FFT (no barriers) ----
    {
        float2* src = FA + (wv << 7);
        float2* dst = FB + (wv << 7);
        #pragma unroll
        for (int s = 1; s <= 7; ++s) {
            const int l = 1 << (s - 1);
            const int pl = lane & (l - 1);
            const int i0 = 2 * lane - pl;
            const float rev = (float)pl * (0.5f / (float)l);   // e^{-i pi pl/l}
            const float cw =  __builtin_amdgcn_cosf(rev);
            const float sw = -__builtin_amdgcn_sinf(rev);
            float2 a = src[lane];
            float2 b = src[lane + 64];
            float tr = cw * b.x - sw * b.y;
            float ti = cw * b.y + sw * b.x;
            dst[i0]     = make_float2(a.x + tr, a.y + ti);
            dst[i0 + l] = make_float2(a.x - tr, a.y - ti);
            float2* tmp = src; src = dst; dst = tmp;
        }
        // 7 stages (odd) -> results in FB
    }
    __syncthreads();

    // ---- combine + rfft unpack ----
    float v[2]; int id[2];
    {
        const float2* Fe = FB;
        const float2* Fo = FB + 128;
        const int k1 = tid + 1;
        const int a = k1 & 127;
        const int b = (128 - a) & 127;       // (-k1) mod 128
        float2 Fea = Fe[a], Foa = Fo[a], Feb = Fe[b], Fob = Fo[b];
        const float revw = (float)k1 * (1.0f / 256.0f);
        const float cw =  __builtin_amdgcn_cosf(revw);
        const float sw = -__builtin_amdgcn_sinf(revw);   // w = e^{-2pi i k1/256}
        float wfr = cw * Foa.x - sw * Foa.y, wfi = cw * Foa.y + sw * Foa.x;
        float cfr = cw * Fob.x + sw * Fob.y, cfi = cw * Fob.y - sw * Fob.x;
        const float revu = (float)k1 * (1.0f / 512.0f);
        const float su = __builtin_amdgcn_sinf(revu);
        const float cu = __builtin_amdgcn_cosf(revu);
        #pragma unroll
        for (int q = 0; q < 2; ++q) {
            const float sgn = q ? -1.f : 1.f;
            float Ax = Fea.x + sgn * wfr, Ay = Fea.y + sgn * wfi;
            float Bx = Feb.x + sgn * cfr, By = Feb.y + sgn * cfi;
            float Er = 0.5f * (Ax + Bx);
            float Ei = 0.5f * (Ay - By);
            float Or = 0.5f * (Ay + By);
            float Oi = 0.5f * (Bx - Ax);
            float cth = q ? -su : cu;
            float sth = q ?  cu : su;
            float Fr = Er + cth * Or + sth * Oi;
            float Fi = Ei + cth * Oi - sth * Or;
            v[q] = sqrtf(Fr * Fr + Fi * Fi);
            id[q] = k1 + 128 * q;
        }
    }

    // ---- wave-local top-3 then cross-wave merge ----
    {
        float vals[3]; int idxs[3];
        #pragma unroll
        for (int kk = 0; kk < 3; ++kk) {
            float bv = v[0]; int bi = id[0];
            if (v[1] > bv || (v[1] == bv && id[1] < bi)) { bv = v[1]; bi = id[1]; }
            #pragma unroll
            for (int off = 32; off >= 1; off >>= 1) {
                float ov = __shfl_xor(bv, off, 64);
                int   oi = __shfl_xor(bi, off, 64);
                if (ov > bv || (ov == bv && oi < bi)) { bv = ov; bi = oi; }
            }
            vals[kk] = bv; idxs[kk] = bi;
            #pragma unroll
            for (int q = 0; q < 2; ++q)
                if (id[q] == bi) v[q] = -1e30f;
        }
        if (lane == 0) {
            #pragma unroll
            for (int kk = 0; kk < 3; ++kk) {
                wtopS[wv * 3 + kk] = vals[kk];
                itopS[wv * 3 + kk] = idxs[kk];
            }
        }
    }
    if (tid < 25) WsumS[tid] = WeffS[tid] + WeffS[25 + tid] + WeffS[50 + tid];
    __syncthreads();
    if (tid == 0) {
        float vv[6]; int ii[6];
        #pragma unroll
        for (int q = 0; q < 6; ++q) { vv[q] = wtopS[q]; ii[q] = itopS[q]; }
        float vals[3]; int idxs[3];
        #pragma unroll
        for (int kk = 0; kk < 3; ++kk) {
            float bv = vv[0]; int bi = ii[0];
            #pragma unroll
            for (int q = 1; q < 6; ++q)
                if (vv[q] > bv || (vv[q] == bv && ii[q] < bi)) { bv = vv[q]; bi = ii[q]; }
            vals[kk] = bv; idxs[kk] = bi;
            #pragma unroll
            for (int q = 0; q < 6; ++q)
                if (ii[q] == bi) vv[q] = -1e30f;
        }
        float m = fmaxf(vals[0], fmaxf(vals[1], vals[2]));
        float e0 = expf(vals[0] - m), e1 = expf(vals[1] - m), e2 = expf(vals[2] - m);
        float inv = 1.0f / (e0 + e1 + e2);
        bwS[0] = e0 * inv; bwS[1] = e1 * inv; bwS[2] = e2 * inv;
        #pragma unroll
        for (int kk = 0; kk < 3; ++kk) {
            int fi = idxs[kk];
            int P = T_ / fi;
            P = P < 32 ? 32 : (P > 512 ? 512 : P);
            int cyc = T_ / P;
            ipS[kk] = P; ipS[3 + kk] = cyc; ipS[6 + kk] = T_ - cyc * P;
        }
    }
    __syncthreads();

    // ---- fold + conv + pools + merged seq ----
    const int P0  = __builtin_amdgcn_readfirstlane(ipS[0]);
    const int P1  = __builtin_amdgcn_readfirstlane(ipS[1]);
    const int P2  = __builtin_amdgcn_readfirstlane(ipS[2]);
    const int cy0 = __builtin_amdgcn_readfirstlane(ipS[3]);
    const int cy1 = __builtin_amdgcn_readfirstlane(ipS[4]);
    const int cy2 = __builtin_amdgcn_readfirstlane(ipS[5]);
    const int bs0 = __builtin_amdgcn_readfirstlane(ipS[6]);
    const int bs1 = __builtin_amdgcn_readfirstlane(ipS[7]);
    const int bs2 = __builtin_amdgcn_readfirstlane(ipS[8]);
    const float bw0 = bwS[0], bw1 = bwS[1], bw2 = bwS[2];
    const float beff = WeffS[75], wr0 = WeffS[76], wr1 = WeffS[77],
                wr2 = WeffS[78], bres = WeffS[79];

    int maxP = P0 > P1 ? P0 : P1; maxP = maxP > P2 ? maxP : P2;
    const bool fastp = (P0 == P1) && (P1 == P2);   // identical folds (~83%)
    const int kcount = fastp ? 1 : 3;
    const int PkA[3]  = {P0, P1, P2};
    const int cykA[3] = {cy0, cy1, cy2};
    const int bskA[3] = {bs0, bs1, bs2};
    const int ccb = wv << 3;            // this wave's cc base: 0 or 8
    const int nchunk = (maxP + 63) >> 6;
    float* mrg = reinterpret_cast<float*>(FA);  // 6 x 64 partials (FFT done)
    const size_t rT = (size_t)r * T_;

    #pragma unroll 1
    for (int ch = 0; ch < nchunk; ++ch) {
        const int p = (ch << 6) + lane;       // both waves cover same p range

        float zacc[8];
        #pragma unroll
        for (int i = 0; i < 8; ++i) zacc[i] = beff;

        // ---- conv: this wave's cc half; source rows hh in [ccb-2, ccb+10) ----
        #pragma unroll 1
        for (int k = 0; k < kcount; ++k) {
            const int P = PkA[k];
            const int cy = cykA[k];
            if (ccb - 2 >= cy) continue;     // wave-uniform: no source rows
            const int bs = bskA[k];
            const float* Wsrc = fastp ? WsumS : (WeffS + k * 25);
            float Wk[5][5];
            #pragma unroll
            for (int i = 0; i < 5; ++i)
                #pragma unroll
                for (int j = 0; j < 5; ++j)
                    Wk[i][j] = Wsrc[i * 5 + j];
            bool mdw[5];
            #pragma unroll
            for (int dw = -2; dw <= 2; ++dw)
                mdw[dw + 2] = ((unsigned)(p + dw) < (unsigned)P);
            const int base = bs + p;         // rowp idx of dw=-2 tap (+2 pad cancels)
            #pragma unroll
            for (int g = 0; g < 3; ++g) {    // 12 rows = 3 groups of 4
                if (ccb - 2 + 4 * g < cy) {  // uniform group guard
                    #pragma unroll
                    for (int h4 = 0; h4 < 4; ++h4) {
                        const int hh = ccb - 2 + 4 * g + h4;
                        const bool vh = (unsigned)hh < (unsigned)cy;
                        const int hoff = vh ? 0 : 4096;          // uniform
                        int a0 = base + hh * P + hoff;
                        a0 = a0 < 0 ? 0 : (a0 > 1031 ? 1031 : a0);  // pad/tail=0
                        float w[5];
                        #pragma unroll
                        for (int dw = 0; dw < 5; ++dw)
                            w[dw] = mdw[dw] ? rowp[a0 + dw] : 0.f;
                        #pragma unroll
                        for (int dh = -2; dh <= 2; ++dh) {
                            const int cl = (4 * g + h4 - 2) - dh;  // compile-time
                            if (cl >= 0 && cl < 8) {
                                #pragma unroll
                                for (int dw = 0; dw < 5; ++dw)
                                    zacc[cl] = fmaf(Wk[dh + 2][dw], w[dw], zacc[cl]);
                            }
                        }
                    }
                }
            }
        }

        // ---- pool partials over this wave's cc half ----
        int cymax = cy0 > cy1 ? cy0 : cy1; cymax = cymax > cy2 ? cymax : cy2;
        float num = 0.f, den = 0.f, mx = -3.402823466e38f;
        float s0 = 0.f, s1 = 0.f, s2 = 0.f;
        const int pl0 = (p < P0), pl1 = (p < P1), pl2 = (p < P2);
        #pragma unroll
        for (int cg = 0; cg < 2; ++cg) {
            if (ccb + 4 * cg < cymax) {      // uniform group guard
                #pragma unroll
                for (int c4 = 0; c4 < 4; ++c4) {
                    const int cc = ccb + 4 * cg + c4;
                    int m0 = (cc < cy0) & pl0;
                    int m1 = (cc < cy1) & pl1;
                    int m2 = (cc < cy2) & pl2;
                    int a0 = 2 + bs0 + cc * P0 + p; a0 = a0 > 1036 ? 1036 : a0;
                    int a1 = 2 + bs1 + cc * P1 + p; a1 = a1 > 1036 ? 1036 : a1;
                    int a2 = 2 + bs2 + cc * P2 + p; a2 = a2 > 1036 ? 1036 : a2;
                    float x0v = m0 ? rowp[a0] : 0.f;
                    float x1v = m1 ? rowp[a1] : 0.f;
                    float x2v = m2 ? rowp[a2] : 0.f;
                    float res = fmaf(wr0, x0v, fmaf(wr1, x1v, fmaf(wr2, x2v, bres)));
                    float z = gelu_fast(zacc[4 * cg + c4]) + res;
                    s0 += x0v; s1 += x1v; s2 += x2v;
                    int mm = m0 | m1 | m2;
                    float cm = mm ? 1.f : 0.f;
                    num += z * cm;
                    den += cm;
                    mx = mm ? fmaxf(mx, z) : mx;
                }
            }
        }

        // ---- cross-wave merge via LDS ----
        if (wv == 1) {
            mrg[lane]       = num;  mrg[64 + lane]  = den;
            mrg[128 + lane] = mx;   mrg[192 + lane] = s0;
            mrg[256 + lane] = s1;   mrg[320 + lane] = s2;
        }
        __syncthreads();
        if (wv == 0) {
            num += mrg[lane];
            den += mrg[64 + lane];
            mx = fmaxf(mx, mrg[128 + lane]);
            s0 += mrg[192 + lane];
            s1 += mrg[256 + lane];
            s2 += mrg[320 + lane];
            float avg = num / (den + FEPS);
            float mpool = (den > 0.f) ? mx : 0.f;
            float seq = 0.f;
            seq = fmaf(bw0, pl0 ? s0 / ((float)cy0 + FEPS) : 0.f, seq);
            seq = fmaf(bw1, pl1 ? s1 / ((float)cy1 + FEPS) : 0.f, seq);
            seq = fmaf(bw2, pl2 ? s2 / ((float)cy2 + FEPS) : 0.f, seq);
            avg_out[rT + p] = avg;
            max_out[rT + p] = mpool;
            seq_out[rT + p] = seq;
        }
        __syncthreads();     // protect mrg before next chunk overwrites
    }

    // ---- zero tail: p in [nchunk*64, 512) ----
    for (int i = (nchunk << 6) + tid; i < T_; i += 128) {
        avg_out[rT + i] = 0.f;
        max_out[rT + i] = 0.f;
        seq_out[rT + i] = 0.f;
    }
}

// ---------- fuse GEMM + gelu ----------
// grid (16 t-tiles, 32 b), 256 threads, 64o x 32t tile, 2o x 4t micro.
__global__ __launch_bounds__(256) void fuse_kernel(
    const float* __restrict__ avgb, const float* __restrict__ maxb,
    const float* __restrict__ seqb,
    const float* __restrict__ wf, const float* __restrict__ bfu,
    float* __restrict__ out)
{
    __shared__ float wT[64][70];    // wT[c][o]
    __shared__ float Bt[64][40];    // Bt[c][t]
    const int tid = threadIdx.x;
    const int b = blockIdx.y;
    const int tt0 = blockIdx.x * 32;
    const int og = tid >> 3;        // 0..31
    const int tg = tid & 7;         // 0..7
    const int o0 = og * 2;
    const int t0 = tg * 4;

    float acc[2][4];
    #pragma unroll
    for (int i = 0; i < 2; ++i)
        #pragma unroll
        for (int j = 0; j < 4; ++j) acc[i][j] = 0.f;

    const float* srcs[3] = {avgb, maxb, seqb};
    for (int g = 0; g < 3; ++g) {
        const float* __restrict__ src = srcs[g];
        #pragma unroll
        for (int it = 0; it < 2; ++it) {
            int idx = tid + it * 256;          // 0..511
            int c = idx >> 3, t4 = idx & 7;
            float4 vv = reinterpret_cast<const float4*>(
                            &src[(b * 64 + c) * 512 + tt0])[t4];
            *reinterpret_cast<float4*>(&Bt[c][t4 * 4]) = vv;
        }
        #pragma unroll
        for (int it = 0; it < 16; ++it) {
            int i = tid + it * 256;            // 0..4095
            int c = i & 63, o = i >> 6;
            wT[c][o] = wf[o * 192 + g * 64 + c];
        }
        __syncthreads();
        for (int c = 0; c < 64; ++c) {
            float2 wv = *reinterpret_cast<const float2*>(&wT[c][o0]);
            float4 bv = *reinterpret_cast<const float4*>(&Bt[c][t0]);
            const float wa[2] = {wv.x, wv.y};
            const float ba[4] = {bv.x, bv.y, bv.z, bv.w};
            #pragma unroll
            for (int i = 0; i < 2; ++i)
                #pragma unroll
                for (int j = 0; j < 4; ++j)
                    acc[i][j] = fmaf(wa[i], ba[j], acc[i][j]);
        }
        __syncthreads();
    }
    #pragma unroll
    for (int i = 0; i < 2; ++i) {
        float bias = bfu[o0 + i];
        float4 o4;
        o4.x = gelu_fast(acc[i][0] + bias);
        o4.y = gelu_fast(acc[i][1] + bias);
        o4.z = gelu_fast(acc[i][2] + bias);
        o4.w = gelu_fast(acc[i][3] + bias);
        *reinterpret_cast<float4*>(
            &out[(b * 64 + (o0 + i)) * 512 + tt0 + t0]) = o4;
    }
}

extern "C" void kernel_launch(void* const* d_in, const int* in_sizes, int n_in,
                              void* d_out, int out_size, void* d_ws, size_t ws_size,
                              hipStream_t stream) {
    const float* feat = (const float*)d_in[0];
    const float* w0  = (const float*)d_in[1];
    const float* b0  = (const float*)d_in[2];
    const float* w1  = (const float*)d_in[3];
    const float* b1  = (const float*)d_in[4];
    const float* w2  = (const float*)d_in[5];
    const float* b2  = (const float*)d_in[6];
    const float* wpj = (const float*)d_in[7];
    const float* bpj = (const float*)d_in[8];
    const float* wr  = (const float*)d_in[9];
    const float* br  = (const float*)d_in[10];
    const float* wf  = (const float*)d_in[11];
    const float* bfu = (const float*)d_in[12];

    float* ws = (float*)d_ws;
    float* avgb = ws;
    float* maxb = ws + (size_t)NROWS * T_;
    float* seqb = ws + 2 * (size_t)NROWS * T_;

    mono_kernel<<<NROWS, 128, 0, stream>>>(feat, w0, b0, w1, b1, w2, b2,
                                           wpj, bpj, wr, br, avgb, maxb, seqb);
    fuse_kernel<<<dim3(16, 32), 256, 0, stream>>>(avgb, maxb, seqb, wf, bfu,
                                                  (float*)d_out);
}

// Round 17
// 43.826 us; speedup vs baseline: 1.5546x; 1.5546x over previous
//
#include <hip/hip_runtime.h>
#include <math.h>

#define B_    32
#define C_    64
#define T_    512
#define NROWS (B_ * C_)
#define CMAX_ 16
#define FEPS  1.1920929e-07f

// gelu via sigmoid form of the tanh approximation (max abs err ~3e-4)
__device__ __forceinline__ float gelu_fast(float x) {
    float y = fmaf(0.044715f * x * x, x, x);
    float e = __builtin_exp2f(-2.3022808f * y);
    return x * __builtin_amdgcn_rcpf(1.0f + e);
}

// ---------------- mono kernel: rFFT + top-3 + fold/conv/pools/seq ----------
// ONE ROW PER 64-THREAD (1-wave) BLOCK. Zero __syncthreads: the 256-pt FFT,
// weight prep, and all LDS producer/consumer pairs are wave-synchronous.
// Top-3 butterfly reduce leaves results in ALL lanes -> params computed
// per-lane, no serialization, no cross-wave merge.
__global__ __launch_bounds__(64) void mono_kernel(
    const float* __restrict__ feat,
    const float* __restrict__ w0, const float* __restrict__ b0,
    const float* __restrict__ w1, const float* __restrict__ b1,
    const float* __restrict__ w2, const float* __restrict__ b2,
    const float* __restrict__ wpj, const float* __restrict__ bpj,
    const float* __restrict__ wr, const float* __restrict__ br,
    float* __restrict__ avg_out, float* __restrict__ max_out,
    float* __restrict__ seq_out)
{
    __shared__ float rowp[1040];         // rowp[2+i] = row[i]; tail zero-filled
    __shared__ __align__(16) float2 FA[256];
    __shared__ __align__(16) float2 FB[256];
    __shared__ float WeffS[80];
    __shared__ float WsumS[25];          // W0+W1+W2 (identical-fold case)

    const int tid = threadIdx.x;         // 0..63
    const int r = blockIdx.x;

    // ---- stage row (8 floats/lane); zero pad + tail ----
    {
        const float4* f4 = reinterpret_cast<const float4*>(feat + (size_t)r * T_);
        float4 v0 = f4[tid], v1 = f4[tid + 64];
        const int b0i = 2 + tid * 4, b1i = 2 + (tid + 64) * 4;
        rowp[b0i] = v0.x; rowp[b0i + 1] = v0.y; rowp[b0i + 2] = v0.z; rowp[b0i + 3] = v0.w;
        rowp[b1i] = v1.x; rowp[b1i + 1] = v1.y; rowp[b1i + 2] = v1.z; rowp[b1i + 3] = v1.w;
    }
    for (int i = 514 + tid; i < 1040; i += 64) rowp[i] = 0.f;
    if (tid < 2) rowp[tid] = 0.f;

    // ---- fold conv weights (wave-synchronous; no barrier) ----
    for (int i = tid; i < 80; i += 64) {
        if (i < 75) {
            int k = i / 25, ij = i % 25, ii = ij / 5, jj = ij % 5;
            float w = wpj[2] * w2[k * 25 + ii * 5 + jj];
            if (ii >= 1 && ii <= 3 && jj >= 1 && jj <= 3)
                w += wpj[1] * w1[k * 9 + (ii - 1) * 3 + (jj - 1)];
            if (ii == 2 && jj == 2) w += wpj[0] * w0[k];
            WeffS[i] = w;
        } else if (i == 75) {
            WeffS[75] = wpj[0] * b0[0] + wpj[1] * b1[0] + wpj[2] * b2[0] + bpj[0];
        } else if (i <= 78) {
            WeffS[i] = wr[i - 76];
        } else {
            WeffS[79] = br[0];
        }
    }
    if (tid < 25) WsumS[tid] = WeffS[tid] + WeffS[25 + tid] + WeffS[50 + tid];

    // ---- pack 512 reals -> 256 complex: z[n] = x[2n] + i x[2n+1] ----
    #pragma unroll
    for (int q = 0; q < 4; ++q) {
        const int n = tid + (q << 6);
        FA[n] = make_float2(rowp[2 + 2 * n], rowp[3 + 2 * n]);
    }

    // ---- 8-stage Stockham 256-pt FFT, 2 butterflies/lane, no barriers ----
    {
        float2* src = FA;
        float2* dst = FB;
        #pragma unroll
        for (int s = 1; s <= 8; ++s) {
            const int l = 1 << (s - 1);
            #pragma unroll
            for (int h = 0; h < 2; ++h) {
                const int j = tid + (h << 6);          // 0..127
                const int pl = j & (l - 1);
                const int i0 = 2 * j - pl;
                const float rev = (float)pl * (0.5f / (float)l);  // e^{-i pi pl/l}
                const float cw =  __builtin_amdgcn_cosf(rev);
                const float sw = -__builtin_amdgcn_sinf(rev);
                float2 a = src[j];
                float2 b = src[j + 128];
                float tr = cw * b.x - sw * b.y;
                float ti = cw * b.y + sw * b.x;
                dst[i0]     = make_float2(a.x + tr, a.y + ti);
                dst[i0 + l] = make_float2(a.x - tr, a.y - ti);
            }
            float2* t = src; src = dst; dst = t;
        }
        // 8 stages (even) -> result back in FA, natural order
    }

    // ---- rfft unpack: 4 bins/lane, k = 1+tid+64q (covers 1..256) ----
    float v[4]; int id[4];
    #pragma unroll
    for (int q = 0; q < 4; ++q) {
        const int k = 1 + tid + (q << 6);
        float2 A  = FA[k & 255];
        float2 Bv = FA[(256 - k) & 255];
        float Er = 0.5f * (A.x + Bv.x);
        float Ei = 0.5f * (A.y - Bv.y);
        float Or = 0.5f * (A.y + Bv.y);
        float Oi = 0.5f * (Bv.x - A.x);
        const float rev = (float)k * (1.0f / 512.0f);
        float sth = __builtin_amdgcn_sinf(rev);
        float cth = __builtin_amdgcn_cosf(rev);
        float Fr = Er + cth * Or + sth * Oi;
        float Fi = Ei + cth * Oi - sth * Or;
        v[q] = sqrtf(Fr * Fr + Fi * Fi);
        id[q] = k;
    }

    // ---- wave top-3 (jax semantics); butterfly leaves result in ALL lanes ----
    float vals[3]; int idxs[3];
    #pragma unroll
    for (int kk = 0; kk < 3; ++kk) {
        float bv = v[0]; int bi = id[0];
        #pragma unroll
        for (int q = 1; q < 4; ++q)
            if (v[q] > bv || (v[q] == bv && id[q] < bi)) { bv = v[q]; bi = id[q]; }
        #pragma unroll
        for (int off = 32; off >= 1; off >>= 1) {
            float ov = __shfl_xor(bv, off, 64);
            int   oi = __shfl_xor(bi, off, 64);
            if (ov > bv || (ov == bv && oi < bi)) { bv = ov; bi = oi; }
        }
        vals[kk] = bv; idxs[kk] = bi;
        #pragma unroll
        for (int q = 0; q < 4; ++q)
            if (id[q] == bi) v[q] = -1e30f;
    }

    // ---- per-lane params (identical in all lanes) ----
    float bw0, bw1, bw2;
    int P_[3], cy_[3], bs_[3];
    {
        float m = fmaxf(vals[0], fmaxf(vals[1], vals[2]));
        float e0 = expf(vals[0] - m), e1 = expf(vals[1] - m), e2 = expf(vals[2] - m);
        float inv = 1.0f / (e0 + e1 + e2);
        bw0 = e0 * inv; bw1 = e1 * inv; bw2 = e2 * inv;
        #pragma unroll
        for (int kk = 0; kk < 3; ++kk) {
            int fi = idxs[kk];
            int P = T_ / fi;
            P = P < 32 ? 32 : (P > 512 ? 512 : P);
            int cyc = T_ / P;
            P_[kk] = P; cy_[kk] = cyc; bs_[kk] = T_ - cyc * P;
        }
    }
    const int P0  = __builtin_amdgcn_readfirstlane(P_[0]);
    const int P1  = __builtin_amdgcn_readfirstlane(P_[1]);
    const int P2  = __builtin_amdgcn_readfirstlane(P_[2]);
    const int cy0 = __builtin_amdgcn_readfirstlane(cy_[0]);
    const int cy1 = __builtin_amdgcn_readfirstlane(cy_[1]);
    const int cy2 = __builtin_amdgcn_readfirstlane(cy_[2]);
    const int bs0 = __builtin_amdgcn_readfirstlane(bs_[0]);
    const int bs1 = __builtin_amdgcn_readfirstlane(bs_[1]);
    const int bs2 = __builtin_amdgcn_readfirstlane(bs_[2]);
    const float beff = WeffS[75], wr0 = WeffS[76], wr1 = WeffS[77],
                wr2 = WeffS[78], bres = WeffS[79];

    int maxP = P0 > P1 ? P0 : P1; maxP = maxP > P2 ? maxP : P2;
    const bool fastp = (P0 == P1) && (P1 == P2);   // identical folds (~83%)
    const int kcount = fastp ? 1 : 3;
    const int PkA[3]  = {P0, P1, P2};
    const int cykA[3] = {cy0, cy1, cy2};
    const int bskA[3] = {bs0, bs1, bs2};
    const size_t rT = (size_t)r * T_;

    #pragma unroll 1
    for (int pc = 0; pc < T_; pc += 64) {
        const int p = pc + tid;
        if (pc >= maxP) {
            avg_out[rT + p] = 0.f;
            max_out[rT + p] = 0.f;
            seq_out[rT + p] = 0.f;
            continue;
        }
        int c0 = (P0 > pc) ? cy0 : 0;
        int c1 = (P1 > pc) ? cy1 : 0;
        int c2 = (P2 > pc) ? cy2 : 0;
        int cymax = c0 > c1 ? c0 : c1; cymax = cymax > c2 ? cymax : c2;

        float zacc[CMAX_];
        #pragma unroll
        for (int i = 0; i < CMAX_; ++i) zacc[i] = beff;

        // ---- conv: kcount passes (1 with summed weights if folds identical) ----
        #pragma unroll 1
        for (int k = 0; k < kcount; ++k) {
            const int P = PkA[k];
            if (pc >= P) continue;          // uniform skip
            const int cy = cykA[k];
            const int bs = bskA[k];
            const float* Wsrc = fastp ? WsumS : (WeffS + k * 25);
            float Wk[5][5];
            #pragma unroll
            for (int i = 0; i < 5; ++i)
                #pragma unroll
                for (int j = 0; j < 5; ++j)
                    Wk[i][j] = Wsrc[i * 5 + j];
            bool mdw[5];
            #pragma unroll
            for (int dw = -2; dw <= 2; ++dw)
                mdw[dw + 2] = ((unsigned)(p + dw) < (unsigned)P);
            const int base = bs + p;        // rowp idx of dw=-2 tap (+2 pad cancels)
            #pragma unroll
            for (int g = 0; g < 4; ++g) {
                if (4 * g < cy) {           // uniform group guard
                    #pragma unroll
                    for (int h4 = 0; h4 < 4; ++h4) {
                        const int hh = 4 * g + h4;
                        const int hoff = (hh < cy) ? 0 : 4096;     // uniform
                        int a0 = base + hh * P + hoff;
                        a0 = a0 > 1031 ? 1031 : a0;                // tail reads 0
                        float w[5];
                        #pragma unroll
                        for (int dw = 0; dw < 5; ++dw)
                            w[dw] = mdw[dw] ? rowp[a0 + dw] : 0.f;
                        #pragma unroll
                        for (int dh = -2; dh <= 2; ++dh) {
                            const int cc = hh - dh;     // compile-time
                            if (cc >= 0 && cc < CMAX_) {
                                #pragma unroll
                                for (int dw = 0; dw < 5; ++dw)
                                    zacc[cc] = fmaf(Wk[dh + 2][dw], w[dw], zacc[cc]);
                            }
                        }
                    }
                }
            }
        }

        // ---- pools + merged branch sums: branch-free groups of 4 ----
        float avg_num = 0.f, den = 0.f, mx = -3.402823466e38f;
        float s0 = 0.f, s1 = 0.f, s2 = 0.f;
        int anyv = 0;
        const int pl0 = (p < P0), pl1 = (p < P1), pl2 = (p < P2);
        #pragma unroll
        for (int cg = 0; cg < 4; ++cg) {
            if (4 * cg < cymax) {           // uniform group guard
                #pragma unroll
                for (int c4 = 0; c4 < 4; ++c4) {
                    const int cc = 4 * cg + c4;
                    int m0 = (cc < cy0) & pl0;
                    int m1 = (cc < cy1) & pl1;
                    int m2 = (cc < cy2) & pl2;
                    int a0 = 2 + bs0 + cc * P0 + p; a0 = a0 > 1036 ? 1036 : a0;
                    int a1 = 2 + bs1 + cc * P1 + p; a1 = a1 > 1036 ? 1036 : a1;
                    int a2 = 2 + bs2 + cc * P2 + p; a2 = a2 > 1036 ? 1036 : a2;
                    float x0v = m0 ? rowp[a0] : 0.f;
                    float x1v = m1 ? rowp[a1] : 0.f;
                    float x2v = m2 ? rowp[a2] : 0.f;
                    float res = fmaf(wr0, x0v, fmaf(wr1, x1v, fmaf(wr2, x2v, bres)));
                    float z = gelu_fast(zacc[cc]) + res;
                    s0 += x0v; s1 += x1v; s2 += x2v;
                    int mm = m0 | m1 | m2;
                    float cm = mm ? 1.f : 0.f;
                    avg_num += z * cm;
                    den += cm;
                    mx = mm ? fmaxf(mx, z) : mx;
                    anyv |= mm;
                }
            }
        }
        float avg = avg_num / (den + FEPS);
        float mpool = anyv ? mx : 0.f;

        float seq = 0.f;
        seq = fmaf(bw0, pl0 ? s0 / ((float)cy0 + FEPS) : 0.f, seq);
        seq = fmaf(bw1, pl1 ? s1 / ((float)cy1 + FEPS) : 0.f, seq);
        seq = fmaf(bw2, pl2 ? s2 / ((float)cy2 + FEPS) : 0.f, seq);

        avg_out[rT + p] = avg;
        max_out[rT + p] = mpool;
        seq_out[rT + p] = seq;
    }
}

// ---------- fuse GEMM + gelu ----------
// grid (16 t-tiles, 32 b), 256 threads, 64o x 32t tile, 2o x 4t micro.
__global__ __launch_bounds__(256) void fuse_kernel(
    const float* __restrict__ avgb, const float* __restrict__ maxb,
    const float* __restrict__ seqb,
    const float* __restrict__ wf, const float* __restrict__ bfu,
    float* __restrict__ out)
{
    __shared__ float wT[64][70];    // wT[c][o]
    __shared__ float Bt[64][40];    // Bt[c][t]
    const int tid = threadIdx.x;
    const int b = blockIdx.y;
    const int tt0 = blockIdx.x * 32;
    const int og = tid >> 3;        // 0..31
    const int tg = tid & 7;         // 0..7
    const int o0 = og * 2;
    const int t0 = tg * 4;

    float acc[2][4];
    #pragma unroll
    for (int i = 0; i < 2; ++i)
        #pragma unroll
        for (int j = 0; j < 4; ++j) acc[i][j] = 0.f;

    const float* srcs[3] = {avgb, maxb, seqb};
    for (int g = 0; g < 3; ++g) {
        const float* __restrict__ src = srcs[g];
        #pragma unroll
        for (int it = 0; it < 2; ++it) {
            int idx = tid + it * 256;          // 0..511
            int c = idx >> 3, t4 = idx & 7;
            float4 vv = reinterpret_cast<const float4*>(
                            &src[(b * 64 + c) * 512 + tt0])[t4];
            *reinterpret_cast<float4*>(&Bt[c][t4 * 4]) = vv;
        }
        #pragma unroll
        for (int it = 0; it < 16; ++it) {
            int i = tid + it * 256;            // 0..4095
            int c = i & 63, o = i >> 6;
            wT[c][o] = wf[o * 192 + g * 64 + c];
        }
        __syncthreads();
        for (int c = 0; c < 64; ++c) {
            float2 wv = *reinterpret_cast<const float2*>(&wT[c][o0]);
            float4 bv = *reinterpret_cast<const float4*>(&Bt[c][t0]);
            const float wa[2] = {wv.x, wv.y};
            const float ba[4] = {bv.x, bv.y, bv.z, bv.w};
            #pragma unroll
            for (int i = 0; i < 2; ++i)
                #pragma unroll
                for (int j = 0; j < 4; ++j)
                    acc[i][j] = fmaf(wa[i], ba[j], acc[i][j]);
        }
        __syncthreads();
    }
    #pragma unroll
    for (int i = 0; i < 2; ++i) {
        float bias = bfu[o0 + i];
        float4 o4;
        o4.x = gelu_fast(acc[i][0] + bias);
        o4.y = gelu_fast(acc[i][1] + bias);
        o4.z = gelu_fast(acc[i][2] + bias);
        o4.w = gelu_fast(acc[i][3] + bias);
        *reinterpret_cast<float4*>(
            &out[(b * 64 + (o0 + i)) * 512 + tt0 + t0]) = o4;
    }
}

extern "C" void kernel_launch(void* const* d_in, const int* in_sizes, int n_in,
                              void* d_out, int out_size, void* d_ws, size_t ws_size,
                              hipStream_t stream) {
    const float* feat = (const float*)d_in[0];
    const float* w0  = (const float*)d_in[1];
    const float* b0  = (const float*)d_in[2];
    const float* w1  = (const float*)d_in[3];
    const float* b1  = (const float*)d_in[4];
    const float* w2  = (const float*)d_in[5];
    const float* b2  = (const float*)d_in[6];
    const float* wpj = (const float*)d_in[7];
    const float* bpj = (const float*)d_in[8];
    const float* wr  = (const float*)d_in[9];
    const float* br  = (const float*)d_in[10];
    const float* wf  = (const float*)d_in[11];
    const float* bfu = (const float*)d_in[12];

    float* ws = (float*)d_ws;
    float* avgb = ws;
    float* maxb = ws + (size_t)NROWS * T_;
    float* seqb = ws + 2 * (size_t)NROWS * T_;

    mono_kernel<<<NROWS, 64, 0, stream>>>(feat, w0, b0, w1, b1, w2, b2,
                                          wpj, bpj, wr, br, avgb, maxb, seqb);
    fuse_kernel<<<dim3(16, 32), 256, 0, stream>>>(avgb, maxb, seqb, wf, bfu,
                                                  (float*)d_out);
}

// Round 18
// 39.147 us; speedup vs baseline: 1.7404x; 1.1195x over previous
//
#include <hip/hip_runtime.h>
#include <math.h>

#define B_    32
#define C_    64
#define T_    512
#define NROWS (B_ * C_)
#define CMAX_ 16
#define FEPS  1.1920929e-07f

// gelu via sigmoid form of the tanh approximation (max abs err ~3e-4)
__device__ __forceinline__ float gelu_fast(float x) {
    float y = fmaf(0.044715f * x * x, x, x);
    float e = __builtin_exp2f(-2.3022808f * y);
    return x * __builtin_amdgcn_rcpf(1.0f + e);
}

// ---------------- mono kernel: rFFT + top-3 + fold/conv/pools/seq ----------
// One row per block, 128 threads (2 waves). R15 structure + "super path" for
// the dominant dense case P0==P1==P2==32 (cy=16, bs=0): 4-way cc-split across
// thread quarters, shfl + one-barrier merge.
__global__ __launch_bounds__(128) void mono_kernel(
    const float* __restrict__ feat,
    const float* __restrict__ w0, const float* __restrict__ b0,
    const float* __restrict__ w1, const float* __restrict__ b1,
    const float* __restrict__ w2, const float* __restrict__ b2,
    const float* __restrict__ wpj, const float* __restrict__ bpj,
    const float* __restrict__ wr, const float* __restrict__ br,
    float* __restrict__ avg_out, float* __restrict__ max_out,
    float* __restrict__ seq_out)
{
    __shared__ float rowp[1040];         // rowp[2+i] = row[i]; tail zero-filled
    __shared__ __align__(16) float2 FA[256];   // FFT ping; later merge buffer
    __shared__ __align__(16) float2 FB[256];
    __shared__ float WeffS[80];
    __shared__ float WsumS[25];          // W0+W1+W2 (identical-fold case)
    __shared__ float wtopS[6];
    __shared__ int   itopS[6];
    __shared__ int   ipS[9];             // P[3], cyc[3], base[3]
    __shared__ float bwS[3];

    const int tid = threadIdx.x;         // 0..127
    const int lane = tid & 63;
    const int wv = tid >> 6;
    const int r = blockIdx.x;

    // ---- stage row into padded LDS; zero tail so no clamps needed ----
    {
        float4 v = reinterpret_cast<const float4*>(feat + (size_t)r * T_)[tid];
        int bi = 2 + tid * 4;
        rowp[bi + 0] = v.x; rowp[bi + 1] = v.y;
        rowp[bi + 2] = v.z; rowp[bi + 3] = v.w;
    }
    for (int i = 514 + tid; i < 1040; i += 128) rowp[i] = 0.f;
    if (tid == 0) { rowp[0] = 0.f; rowp[1] = 0.f; }
    if (tid < 80) {
        int i = tid;
        if (i < 75) {
            int k = i / 25, ij = i % 25, ii = ij / 5, jj = ij % 5;
            float w = wpj[2] * w2[k * 25 + ii * 5 + jj];
            if (ii >= 1 && ii <= 3 && jj >= 1 && jj <= 3)
                w += wpj[1] * w1[k * 9 + (ii - 1) * 3 + (jj - 1)];
            if (ii == 2 && jj == 2) w += wpj[0] * w0[k];
            WeffS[i] = w;
        } else if (i == 75) {
            WeffS[75] = wpj[0] * b0[0] + wpj[1] * b1[0] + wpj[2] * b2[0] + bpj[0];
        } else if (i <= 78) {
            WeffS[i] = wr[i - 76];
        } else {
            WeffS[79] = br[0];
        }
    }
    __syncthreads();

    // ---- pack: wave wv owns z_wv[n] = x[4n+2wv] + i x[4n+1+2wv], n=0..127 ----
    {
        float2* Fw = FA + (wv << 7);
        #pragma unroll
        for (int n = lane; n < 128; n += 64)
            Fw[n] = make_float2(rowp[2 + 4 * n + 2 * wv], rowp[3 + 4 * n + 2 * wv]);
    }

    // ---- 7-stage wave-local Stockham 128-pt FFT (no barriers) ----
    {
        float2* src = FA + (wv << 7);
        float2* dst = FB + (wv << 7);
        #pragma unroll
        for (int s = 1; s <= 7; ++s) {
            const int l = 1 << (s - 1);
            const int pl = lane & (l - 1);
            const int i0 = 2 * lane - pl;
            const float rev = (float)pl * (0.5f / (float)l);   // e^{-i pi pl/l}
            const float cw =  __builtin_amdgcn_cosf(rev);
            const float sw = -__builtin_amdgcn_sinf(rev);
            float2 a = src[lane];
            float2 b = src[lane + 64];
            float tr = cw * b.x - sw * b.y;
            float ti = cw * b.y + sw * b.x;
            dst[i0]     = make_float2(a.x + tr, a.y + ti);
            dst[i0 + l] = make_float2(a.x - tr, a.y - ti);
            float2* tmp = src; src = dst; dst = tmp;
        }
        // 7 stages (odd) -> results in FB
    }
    __syncthreads();

    // ---- combine + rfft unpack ----
    float v[2]; int id[2];
    {
        const float2* Fe = FB;
        const float2* Fo = FB + 128;
        const int k1 = tid + 1;
        const int a = k1 & 127;
        const int b = (128 - a) & 127;       // (-k1) mod 128
        float2 Fea = Fe[a], Foa = Fo[a], Feb = Fe[b], Fob = Fo[b];
        const float revw = (float)k1 * (1.0f / 256.0f);
        const float cw =  __builtin_amdgcn_cosf(revw);
        const float sw = -__builtin_amdgcn_sinf(revw);   // w = e^{-2pi i k1/256}
        float wfr = cw * Foa.x - sw * Foa.y, wfi = cw * Foa.y + sw * Foa.x;
        float cfr = cw * Fob.x + sw * Fob.y, cfi = cw * Fob.y - sw * Fob.x;
        const float revu = (float)k1 * (1.0f / 512.0f);
        const float su = __builtin_amdgcn_sinf(revu);
        const float cu = __builtin_amdgcn_cosf(revu);
        #pragma unroll
        for (int q = 0; q < 2; ++q) {
            const float sgn = q ? -1.f : 1.f;
            float Ax = Fea.x + sgn * wfr, Ay = Fea.y + sgn * wfi;
            float Bx = Feb.x + sgn * cfr, By = Feb.y + sgn * cfi;
            float Er = 0.5f * (Ax + Bx);
            float Ei = 0.5f * (Ay - By);
            float Or = 0.5f * (Ay + By);
            float Oi = 0.5f * (Bx - Ax);
            float cth = q ? -su : cu;
            float sth = q ?  cu : su;
            float Fr = Er + cth * Or + sth * Oi;
            float Fi = Ei + cth * Oi - sth * Or;
            v[q] = sqrtf(Fr * Fr + Fi * Fi);
            id[q] = k1 + 128 * q;
        }
    }

    // ---- wave-local top-3 then cross-wave merge ----
    {
        float vals[3]; int idxs[3];
        #pragma unroll
        for (int kk = 0; kk < 3; ++kk) {
            float bv = v[0]; int bi = id[0];
            if (v[1] > bv || (v[1] == bv && id[1] < bi)) { bv = v[1]; bi = id[1]; }
            #pragma unroll
            for (int off = 32; off >= 1; off >>= 1) {
                float ov = __shfl_xor(bv, off, 64);
                int   oi = __shfl_xor(bi, off, 64);
                if (ov > bv || (ov == bv && oi < bi)) { bv = ov; bi = oi; }
            }
            vals[kk] = bv; idxs[kk] = bi;
            #pragma unroll
            for (int q = 0; q < 2; ++q)
                if (id[q] == bi) v[q] = -1e30f;
        }
        if (lane == 0) {
            #pragma unroll
            for (int kk = 0; kk < 3; ++kk) {
                wtopS[wv * 3 + kk] = vals[kk];
                itopS[wv * 3 + kk] = idxs[kk];
            }
        }
    }
    if (tid < 25) WsumS[tid] = WeffS[tid] + WeffS[25 + tid] + WeffS[50 + tid];
    __syncthreads();
    if (tid == 0) {
        float vv[6]; int ii[6];
        #pragma unroll
        for (int q = 0; q < 6; ++q) { vv[q] = wtopS[q]; ii[q] = itopS[q]; }
        float vals[3]; int idxs[3];
        #pragma unroll
        for (int kk = 0; kk < 3; ++kk) {
            float bv = vv[0]; int bi = ii[0];
            #pragma unroll
            for (int q = 1; q < 6; ++q)
                if (vv[q] > bv || (vv[q] == bv && ii[q] < bi)) { bv = vv[q]; bi = ii[q]; }
            vals[kk] = bv; idxs[kk] = bi;
            #pragma unroll
            for (int q = 0; q < 6; ++q)
                if (ii[q] == bi) vv[q] = -1e30f;
        }
        float m = fmaxf(vals[0], fmaxf(vals[1], vals[2]));
        float e0 = expf(vals[0] - m), e1 = expf(vals[1] - m), e2 = expf(vals[2] - m);
        float inv = 1.0f / (e0 + e1 + e2);
        bwS[0] = e0 * inv; bwS[1] = e1 * inv; bwS[2] = e2 * inv;
        #pragma unroll
        for (int kk = 0; kk < 3; ++kk) {
            int fi = idxs[kk];
            int P = T_ / fi;
            P = P < 32 ? 32 : (P > 512 ? 512 : P);
            int cyc = T_ / P;
            ipS[kk] = P; ipS[3 + kk] = cyc; ipS[6 + kk] = T_ - cyc * P;
        }
    }
    __syncthreads();

    // ---- params ----
    const int P0  = __builtin_amdgcn_readfirstlane(ipS[0]);
    const int P1  = __builtin_amdgcn_readfirstlane(ipS[1]);
    const int P2  = __builtin_amdgcn_readfirstlane(ipS[2]);
    const int cy0 = __builtin_amdgcn_readfirstlane(ipS[3]);
    const int cy1 = __builtin_amdgcn_readfirstlane(ipS[4]);
    const int cy2 = __builtin_amdgcn_readfirstlane(ipS[5]);
    const int bs0 = __builtin_amdgcn_readfirstlane(ipS[6]);
    const int bs1 = __builtin_amdgcn_readfirstlane(ipS[7]);
    const int bs2 = __builtin_amdgcn_readfirstlane(ipS[8]);
    const float bw0 = bwS[0], bw1 = bwS[1], bw2 = bwS[2];
    const float beff = WeffS[75], wr0 = WeffS[76], wr1 = WeffS[77],
                wr2 = WeffS[78], bres = WeffS[79];
    const size_t rT = (size_t)r * T_;

    int maxP = P0 > P1 ? P0 : P1; maxP = maxP > P2 ? maxP : P2;
    const bool fastp = (P0 == P1) && (P1 == P2);   // identical folds (~83%)

    // ================= SUPER PATH: P==32 dense (cy=16, bs=0) =================
    if (fastp && P0 == 32) {
        const int p = tid & 31;          // output column
        const int q = tid >> 5;          // cc quarter: cc in [4q, 4q+4)
        float Wk[5][5];
        #pragma unroll
        for (int i = 0; i < 5; ++i)
            #pragma unroll
            for (int j = 0; j < 5; ++j)
                Wk[i][j] = WsumS[i * 5 + j];
        bool mdw[5];
        #pragma unroll
        for (int dw = 0; dw < 5; ++dw)
            mdw[dw] = ((unsigned)(p + dw - 2) < 32u);

        float zq[4];
        #pragma unroll
        for (int i = 0; i < 4; ++i) zq[i] = beff;

        const int hbase = (q << 2) - 2;
        #pragma unroll
        for (int hr = 0; hr < 8; ++hr) {
            const int hh = hbase + hr;                     // source row
            const bool hv = ((unsigned)hh < 16u);
            int ab = (hh << 5) + p;                        // rowp idx of dwi=0 tap
            ab = ab < 0 ? 0 : ab;                          // masked lanes read 0-pad
            float w[5];
            #pragma unroll
            for (int dw = 0; dw < 5; ++dw)
                w[dw] = (hv && mdw[dw]) ? rowp[ab + dw] : 0.f;
            #pragma unroll
            for (int dh = 0; dh < 5; ++dh) {
                const int cl = hr - dh;                    // compile-time
                if (cl >= 0 && cl < 4) {
                    #pragma unroll
                    for (int dw = 0; dw < 5; ++dw)
                        zq[cl] = fmaf(Wk[dh][dw], w[dw], zq[cl]);
                }
            }
        }

        // pools over this quarter's 4 cc (all cells valid: den=16 total)
        const float wrS  = wr0 + wr1 + wr2;
        const float bwS3 = bw0 + bw1 + bw2;
        float num = 0.f, mx = -3.402823466e38f, sx = 0.f;
        #pragma unroll
        for (int c4 = 0; c4 < 4; ++c4) {
            const int cc = (q << 2) + c4;
            float xv = rowp[2 + (cc << 5) + p];
            float z = gelu_fast(zq[c4]) + fmaf(wrS, xv, bres);
            num += z; sx += xv; mx = fmaxf(mx, z);
        }
        // in-wave merge (quarters q and q+1 within each wave share p)
        num += __shfl_xor(num, 32, 64);
        sx  += __shfl_xor(sx, 32, 64);
        mx   = fmaxf(mx, __shfl_xor(mx, 32, 64));
        // cross-wave merge via LDS (FA is dead now)
        float* mrg = reinterpret_cast<float*>(FA);
        if (wv == 1 && lane < 32) {
            mrg[lane] = num; mrg[32 + lane] = sx; mrg[64 + lane] = mx;
        }
        __syncthreads();                 // wave-uniform branch: both waves arrive
        if (wv == 0 && lane < 32) {
            num += mrg[lane];
            sx  += mrg[32 + lane];
            mx   = fmaxf(mx, mrg[64 + lane]);
            const float rden = 1.0f / (16.0f + FEPS);
            avg_out[rT + p] = num * rden;
            max_out[rT + p] = mx;
            seq_out[rT + p] = bwS3 * sx * rden;
        }
        for (int i = 32 + tid; i < T_; i += 128) {
            avg_out[rT + i] = 0.f;
            max_out[rT + i] = 0.f;
            seq_out[rT + i] = 0.f;
        }
        return;
    }

    // ================= GENERAL PATH (R15, unchanged) =================
    const int kcount = fastp ? 1 : 3;
    const int PkA[3]  = {P0, P1, P2};
    const int cykA[3] = {cy0, cy1, cy2};
    const int bskA[3] = {bs0, bs1, bs2};

    #pragma unroll 1
    for (int pc = 0; pc < T_; pc += 128) {
        const int p = pc + tid;
        const int wb = __builtin_amdgcn_readfirstlane(pc + (tid & 64));
        if (wb >= maxP) {
            avg_out[rT + p] = 0.f;
            max_out[rT + p] = 0.f;
            seq_out[rT + p] = 0.f;
            continue;
        }
        int c0 = (P0 > wb) ? cy0 : 0;
        int c1 = (P1 > wb) ? cy1 : 0;
        int c2 = (P2 > wb) ? cy2 : 0;
        int cymax = c0 > c1 ? c0 : c1; cymax = cymax > c2 ? cymax : c2;
        cymax = __builtin_amdgcn_readfirstlane(cymax);

        float zacc[CMAX_];
        #pragma unroll
        for (int i = 0; i < CMAX_; ++i) zacc[i] = beff;

        #pragma unroll 1
        for (int k = 0; k < kcount; ++k) {
            const int P = PkA[k];
            if (wb >= P) continue;          // wave-uniform skip
            const int cy = cykA[k];
            const int bs = bskA[k];
            const float* Wsrc = fastp ? WsumS : (WeffS + k * 25);
            float Wk[5][5];
            #pragma unroll
            for (int i = 0; i < 5; ++i)
                #pragma unroll
                for (int j = 0; j < 5; ++j)
                    Wk[i][j] = Wsrc[i * 5 + j];
            bool mdw[5];
            #pragma unroll
            for (int dw = -2; dw <= 2; ++dw)
                mdw[dw + 2] = ((unsigned)(p + dw) < (unsigned)P);
            const int base = bs + p;
            #pragma unroll
            for (int g = 0; g < 4; ++g) {
                if (4 * g < cy) {           // uniform group guard
                    #pragma unroll
                    for (int h4 = 0; h4 < 4; ++h4) {
                        const int hh = 4 * g + h4;
                        const int hoff = (hh < cy) ? 0 : 4096;     // uniform
                        int a0 = base + hh * P + hoff;
                        a0 = a0 > 1031 ? 1031 : a0;                // tail reads 0
                        float w[5];
                        #pragma unroll
                        for (int dw = 0; dw < 5; ++dw)
                            w[dw] = mdw[dw] ? rowp[a0 + dw] : 0.f;
                        #pragma unroll
                        for (int dh = -2; dh <= 2; ++dh) {
                            const int cc = hh - dh;     // compile-time
                            if (cc >= 0 && cc < CMAX_) {
                                #pragma unroll
                                for (int dw = 0; dw < 5; ++dw)
                                    zacc[cc] = fmaf(Wk[dh + 2][dw], w[dw], zacc[cc]);
                            }
                        }
                    }
                }
            }
        }

        float avg_num = 0.f, den = 0.f, mx = -3.402823466e38f;
        float s0 = 0.f, s1 = 0.f, s2 = 0.f;
        int anyv = 0;
        const int pl0 = (p < P0), pl1 = (p < P1), pl2 = (p < P2);
        #pragma unroll
        for (int cg = 0; cg < 4; ++cg) {
            if (4 * cg < cymax) {           // uniform group guard
                #pragma unroll
                for (int c4 = 0; c4 < 4; ++c4) {
                    const int cc = 4 * cg + c4;
                    int m0 = (cc < cy0) & pl0;
                    int m1 = (cc < cy1) & pl1;
                    int m2 = (cc < cy2) & pl2;
                    int a0 = 2 + bs0 + cc * P0 + p; a0 = a0 > 1036 ? 1036 : a0;
                    int a1 = 2 + bs1 + cc * P1 + p; a1 = a1 > 1036 ? 1036 : a1;
                    int a2 = 2 + bs2 + cc * P2 + p; a2 = a2 > 1036 ? 1036 : a2;
                    float x0v = m0 ? rowp[a0] : 0.f;
                    float x1v = m1 ? rowp[a1] : 0.f;
                    float x2v = m2 ? rowp[a2] : 0.f;
                    float res = fmaf(wr0, x0v, fmaf(wr1, x1v, fmaf(wr2, x2v, bres)));
                    float z = gelu_fast(zacc[cc]) + res;
                    s0 += x0v; s1 += x1v; s2 += x2v;
                    int mm = m0 | m1 | m2;
                    float cm = mm ? 1.f : 0.f;
                    avg_num += z * cm;
                    den += cm;
                    mx = mm ? fmaxf(mx, z) : mx;
                    anyv |= mm;
                }
            }
        }
        float avg = avg_num / (den + FEPS);
        float mpool = anyv ? mx : 0.f;

        float seq = 0.f;
        seq = fmaf(bw0, pl0 ? s0 / ((float)cy0 + FEPS) : 0.f, seq);
        seq = fmaf(bw1, pl1 ? s1 / ((float)cy1 + FEPS) : 0.f, seq);
        seq = fmaf(bw2, pl2 ? s2 / ((float)cy2 + FEPS) : 0.f, seq);

        avg_out[rT + p] = avg;
        max_out[rT + p] = mpool;
        seq_out[rT + p] = seq;
    }
}

// ---------- fuse GEMM + gelu ----------
// grid (16 t-tiles, 32 b), 256 threads, 64o x 32t tile, 2o x 4t micro.
__global__ __launch_bounds__(256) void fuse_kernel(
    const float* __restrict__ avgb, const float* __restrict__ maxb,
    const float* __restrict__ seqb,
    const float* __restrict__ wf, const float* __restrict__ bfu,
    float* __restrict__ out)
{
    __shared__ float wT[64][70];    // wT[c][o]
    __shared__ float Bt[64][40];    // Bt[c][t]
    const int tid = threadIdx.x;
    const int b = blockIdx.y;
    const int tt0 = blockIdx.x * 32;
    const int og = tid >> 3;        // 0..31
    const int tg = tid & 7;         // 0..7
    const int o0 = og * 2;
    const int t0 = tg * 4;

    float acc[2][4];
    #pragma unroll
    for (int i = 0; i < 2; ++i)
        #pragma unroll
        for (int j = 0; j < 4; ++j) acc[i][j] = 0.f;

    const float* srcs[3] = {avgb, maxb, seqb};
    for (int g = 0; g < 3; ++g) {
        const float* __restrict__ src = srcs[g];
        #pragma unroll
        for (int it = 0; it < 2; ++it) {
            int idx = tid + it * 256;          // 0..511
            int c = idx >> 3, t4 = idx & 7;
            float4 vv = reinterpret_cast<const float4*>(
                            &src[(b * 64 + c) * 512 + tt0])[t4];
            *reinterpret_cast<float4*>(&Bt[c][t4 * 4]) = vv;
        }
        #pragma unroll
        for (int it = 0; it < 16; ++it) {
            int i = tid + it * 256;            // 0..4095
            int c = i & 63, o = i >> 6;
            wT[c][o] = wf[o * 192 + g * 64 + c];
        }
        __syncthreads();
        for (int c = 0; c < 64; ++c) {
            float2 wv = *reinterpret_cast<const float2*>(&wT[c][o0]);
            float4 bv = *reinterpret_cast<const float4*>(&Bt[c][t0]);
            const float wa[2] = {wv.x, wv.y};
            const float ba[4] = {bv.x, bv.y, bv.z, bv.w};
            #pragma unroll
            for (int i = 0; i < 2; ++i)
                #pragma unroll
                for (int j = 0; j < 4; ++j)
                    acc[i][j] = fmaf(wa[i], ba[j], acc[i][j]);
        }
        __syncthreads();
    }
    #pragma unroll
    for (int i = 0; i < 2; ++i) {
        float bias = bfu[o0 + i];
        float4 o4;
        o4.x = gelu_fast(acc[i][0] + bias);
        o4.y = gelu_fast(acc[i][1] + bias);
        o4.z = gelu_fast(acc[i][2] + bias);
        o4.w = gelu_fast(acc[i][3] + bias);
        *reinterpret_cast<float4*>(
            &out[(b * 64 + (o0 + i)) * 512 + tt0 + t0]) = o4;
    }
}

extern "C" void kernel_launch(void* const* d_in, const int* in_sizes, int n_in,
                              void* d_out, int out_size, void* d_ws, size_t ws_size,
                              hipStream_t stream) {
    const float* feat = (const float*)d_in[0];
    const float* w0  = (const float*)d_in[1];
    const float* b0  = (const float*)d_in[2];
    const float* w1  = (const float*)d_in[3];
    const float* b1  = (const float*)d_in[4];
    const float* w2  = (const float*)d_in[5];
    const float* b2  = (const float*)d_in[6];
    const float* wpj = (const float*)d_in[7];
    const float* bpj = (const float*)d_in[8];
    const float* wr  = (const float*)d_in[9];
    const float* br  = (const float*)d_in[10];
    const float* wf  = (const float*)d_in[11];
    const float* bfu = (const float*)d_in[12];

    float* ws = (float*)d_ws;
    float* avgb = ws;
    float* maxb = ws + (size_t)NROWS * T_;
    float* seqb = ws + 2 * (size_t)NROWS * T_;

    mono_kernel<<<NROWS, 128, 0, stream>>>(feat, w0, b0, w1, b1, w2, b2,
                                           wpj, bpj, wr, br, avgb, maxb, seqb);
    fuse_kernel<<<dim3(16, 32), 256, 0, stream>>>(avgb, maxb, seqb, wf, bfu,
                                                  (float*)d_out);
}